// Round 12
// baseline (179.944 us; speedup 1.0000x reference)
//
#include <hip/hip_runtime.h>
#include <cstdint>
#include <cstddef>

typedef unsigned short ushort_t;
typedef unsigned int uint_t;

typedef __bf16 bf16x8 __attribute__((ext_vector_type(8)));
typedef float floatx4 __attribute__((ext_vector_type(4)));

#define B_ 16
#define N1_ 4096
#define N2_ 1024
#define C1_ 128
#define C2_ 256
#define DIN_ 384
#define DOUT_ 256
#define M_ (B_ * N1_)  // 65536

// ---------------- helpers ----------------

__device__ __forceinline__ ushort_t f2bf(float f) {
  unsigned int u = __builtin_bit_cast(unsigned int, f);
  u = (u + 0x7fffu + ((u >> 16) & 1u)) >> 16;  // RNE
  return (ushort_t)u;
}

// ---------------- kernel P: weight swizzle + bf16 convert ----------------
// W1s[t][n][kk] = bf16(W1[t*32+kk][n]), t=0..11, n=0..255, kk=0..31

__global__ __launch_bounds__(256) void prep_kernel(
    const float* __restrict__ W1, const float* __restrict__ W2,
    ushort_t* __restrict__ W1s, ushort_t* __restrict__ W2s) {
  int e = blockIdx.x * 256 + threadIdx.x;
  if (e < DOUT_ * DIN_) {  // 98304
    int kk = e & 31, n = (e >> 5) & 255, t = e >> 13;
    W1s[e] = f2bf(W1[(size_t)(t * 32 + kk) * DOUT_ + n]);
  }
  if (e < DOUT_ * DOUT_) {  // 65536
    int kk = e & 31, n = (e >> 5) & 255, t = e >> 13;
    W2s[e] = f2bf(W2[(size_t)(t * 32 + kk) * DOUT_ + n]);
  }
}

// ---------------- knn primitives (verbatim from verified kernels) ----------

__device__ __forceinline__ void ins_exact(float& s0, float& s1, float& s2,
                                          int& i0, int& i1, int& i2,
                                          float d, int p) {
  float ns2 = __builtin_amdgcn_fmed3f(d, s1, s2);
  float ns1 = __builtin_amdgcn_fmed3f(d, s0, s1);
  float ns0 = fminf(d, s0);
  bool c0 = d < s0, c1 = d < s1, c2 = d < s2;
  i2 = c1 ? i1 : (c2 ? p : i2);
  i1 = c0 ? i0 : (c1 ? p : i1);
  i0 = c0 ? p : i0;
  s0 = ns0; s1 = ns1; s2 = ns2;
}

__device__ __forceinline__ void ins_merge(float& s0, float& s1, float& s2,
                                          int& i0, int& i1, int& i2,
                                          float e, int j) {
  bool t0 = (e < s0) || (e == s0 && j < i0);
  bool t1 = (e < s1) || (e == s1 && j < i1);
  bool t2 = (e < s2) || (e == s2 && j < i2);
  s2 = t1 ? s1 : (t2 ? e : s2);
  i2 = t1 ? i1 : (t2 ? j : i2);
  s1 = t0 ? s0 : (t1 ? e : s1);
  i1 = t0 ? i0 : (t1 ? j : i1);
  s0 = t0 ? e : s0;
  i0 = t0 ? j : i0;
}

// ---------------- fully fused: knn + build + GEMM1 + GEMM2 ----------------
// R11 structure (179.9 us verified: 32 rows/block, 2048 blocks, 24.75 KB
// LDS) with TWO independent changes:
//  (a) knn ILP4: four interleaved chains (p = sub+{0,8,16,24}, stride 32,
//      32 iters), folded D,C,B -> A with the R6-verified index-tiebreak
//      merge. Scan set and tie semantics unchanged. Costs ~12 VGPR;
//      knn state is dead before GEMM regs go live (barrier-separated
//      phases, same thread) -> R9/R10 spill mode excluded.
//  (b) XCD-aware bijective block swizzle: swz = (bid&7)*256 + (bid>>3).
//      2048 blocks % 8 XCDs == 0 -> bijective. Each XCD gets 256
//      contiguous blocks = exactly 2 batches, so its 4 MiB L2 holds the
//      2 MB of feat2+xyz2 those blocks gather (vs dispatch-order luck).

__global__ __launch_bounds__(256, 2) void fused_kernel(
    const float* __restrict__ xyz1, const float* __restrict__ xyz2,
    const float* __restrict__ feat1, const float* __restrict__ feat2,
    const ushort_t* __restrict__ W1s, const float* __restrict__ b1,
    const ushort_t* __restrict__ W2s, const float* __restrict__ b2,
    float* __restrict__ out) {
  __shared__ __align__(16) ushort_t As[32 * 384];  // 24 KB; xs4 (16 KB) + HS (16 KB) alias it
  __shared__ int idxL[32 * 3];
  __shared__ float wL[32 * 3];

  const int tid = threadIdx.x;
  const int wave = tid >> 6;
  const int lane = tid & 63;
  const int m = lane & 15;
  const int q = lane >> 4;
  // XCD swizzle: 2048 wgs, 8 XCDs, 256 contiguous wgs per XCD (= 2 batches)
  const int bid = blockIdx.x;
  const int swz = (bid & 7) * ((M_ / 32) >> 3) + (bid >> 3);
  const int row0 = swz * 32;
  const int b = row0 >> 12;

  // ---- stage xyz2 batch slice into LDS (aliases As front 16 KB) ----
  float4* xs4 = (float4*)As;
  {
    const float4* p24 = (const float4*)(xyz2 + (size_t)b * (N2_ * 3));
    float4 A = p24[3 * tid + 0];
    float4 Bv = p24[3 * tid + 1];
    float4 Cv = p24[3 * tid + 2];
    xs4[4 * tid + 0] = make_float4(A.x, A.y, A.z, 0.0f);
    xs4[4 * tid + 1] = make_float4(A.w, Bv.x, Bv.y, 0.0f);
    xs4[4 * tid + 2] = make_float4(Bv.z, Bv.w, Cv.x, 0.0f);
    xs4[4 * tid + 3] = make_float4(Cv.y, Cv.z, Cv.w, 0.0f);
  }
  __syncthreads();

  // ---- knn: 32 rows, 8 subs/row, ILP4 quad chain ----
  {
    const int g = tid >> 3;  // 0..31
    const int sub = tid & 7;
    const int row = row0 + g;
    const float* p1 = xyz1 + (size_t)row * 3;
    float x1 = p1[0], y1 = p1[1], z1 = p1[2];

    float s0[4], s1[4], s2[4];
    int i0[4], i1[4], i2[4];
#pragma unroll
    for (int r = 0; r < 4; ++r) {
      s0[r] = 3.0e38f; s1[r] = 3.0e38f; s2[r] = 3.0e38f;
      i0[r] = 0; i1[r] = 0; i2[r] = 0;
    }

    int p0 = sub, p1c = sub + 8, p2c = sub + 16, p3c = sub + 24;
#pragma unroll 4
    for (int t = 0; t < N2_ / 32; ++t) {  // 32 iters, 4 candidates each
      float4 q0 = xs4[p0];
      float4 q1 = xs4[p1c];
      float4 q2 = xs4[p2c];
      float4 q3 = xs4[p3c];
      {
        float dx = x1 - q0.x, dy = y1 - q0.y, dz = z1 - q0.z;
        float d = dx * dx + dy * dy + dz * dz;
        ins_exact(s0[0], s1[0], s2[0], i0[0], i1[0], i2[0], d, p0);
      }
      {
        float dx = x1 - q1.x, dy = y1 - q1.y, dz = z1 - q1.z;
        float d = dx * dx + dy * dy + dz * dz;
        ins_exact(s0[1], s1[1], s2[1], i0[1], i1[1], i2[1], d, p1c);
      }
      {
        float dx = x1 - q2.x, dy = y1 - q2.y, dz = z1 - q2.z;
        float d = dx * dx + dy * dy + dz * dz;
        ins_exact(s0[2], s1[2], s2[2], i0[2], i1[2], i2[2], d, p2c);
      }
      {
        float dx = x1 - q3.x, dy = y1 - q3.y, dz = z1 - q3.z;
        float d = dx * dx + dy * dy + dz * dz;
        ins_exact(s0[3], s1[3], s2[3], i0[3], i1[3], i2[3], d, p3c);
      }
      p0 += 32; p1c += 32; p2c += 32; p3c += 32;
    }

    // fold chains 1,2,3 into chain 0 (index-tiebreak; order independent)
#pragma unroll
    for (int r = 1; r < 4; ++r) {
      ins_merge(s0[0], s1[0], s2[0], i0[0], i1[0], i2[0], s0[r], i0[r]);
      ins_merge(s0[0], s1[0], s2[0], i0[0], i1[0], i2[0], s1[r], i1[r]);
      ins_merge(s0[0], s1[0], s2[0], i0[0], i1[0], i2[0], s2[r], i2[r]);
    }

#pragma unroll
    for (int mm = 1; mm <= 4; mm <<= 1) {
      float e0 = __shfl_xor(s0[0], mm), e1 = __shfl_xor(s1[0], mm), e2 = __shfl_xor(s2[0], mm);
      int j0 = __shfl_xor(i0[0], mm), j1 = __shfl_xor(i1[0], mm), j2 = __shfl_xor(i2[0], mm);
      ins_merge(s0[0], s1[0], s2[0], i0[0], i1[0], i2[0], e0, j0);
      ins_merge(s0[0], s1[0], s2[0], i0[0], i1[0], i2[0], e1, j1);
      ins_merge(s0[0], s1[0], s2[0], i0[0], i1[0], i2[0], e2, j2);
    }

    if (sub == 0) {
      float r0 = 1.0f / fmaxf(s0[0], 1e-10f);
      float r1 = 1.0f / fmaxf(s1[0], 1e-10f);
      float r2 = 1.0f / fmaxf(s2[0], 1e-10f);
      float s = 1.0f / (r0 + r1 + r2);
      idxL[g * 3 + 0] = i0[0];
      idxL[g * 3 + 1] = i1[0];
      idxL[g * 3 + 2] = i2[0];
      wL[g * 3 + 0] = r0 * s;
      wL[g * 3 + 1] = r1 * s;
      wL[g * 3 + 2] = r2 * s;
    }
  }
  __syncthreads();  // all xs4 reads done before build overwrites As

  // ---- build phase: As[t][row][kk], elem off = t*1024 + row*32 + kk ----
#pragma unroll 4
  for (int it = 0; it < 8; ++it) {
    int rl = wave * 8 + it;
    int row = row0 + rl;
    int i0 = idxL[rl * 3 + 0], i1 = idxL[rl * 3 + 1], i2 = idxL[rl * 3 + 2];
    float w0 = wL[rl * 3 + 0], w1 = wL[rl * 3 + 1], w2 = wL[rl * 3 + 2];

    const float4* f0 = (const float4*)(feat2 + ((size_t)b * N2_ + i0) * C2_);
    const float4* f1 = (const float4*)(feat2 + ((size_t)b * N2_ + i1) * C2_);
    const float4* f2 = (const float4*)(feat2 + ((size_t)b * N2_ + i2) * C2_);
    float4 a = f0[lane];
    float4 c = f1[lane];
    float4 d = f2[lane];
    float vx = w0 * a.x + w1 * c.x + w2 * d.x;
    float vy = w0 * a.y + w1 * c.y + w2 * d.y;
    float vz = w0 * a.z + w1 * c.z + w2 * d.z;
    float vw = w0 * a.w + w1 * c.w + w2 * d.w;
    // cols 4*lane .. 4*lane+3 (never straddle a 32-col tile)
    uint_t lo = (uint_t)f2bf(vx) | ((uint_t)f2bf(vy) << 16);
    uint_t hi = (uint_t)f2bf(vz) | ((uint_t)f2bf(vw) << 16);
    int e = (lane >> 3) * 1024 + rl * 32 + ((4 * lane) & 31);
    *(uint2*)&As[e] = make_uint2(lo, hi);

    // feat1: cols 256 + 2*lane, 2*lane+1
    float2 t1 = ((const float2*)(feat1 + (size_t)row * C1_))[lane];
    uint_t pk = (uint_t)f2bf(t1.x) | ((uint_t)f2bf(t1.y) << 16);
    int e1 = (8 + (lane >> 4)) * 1024 + rl * 32 + ((2 * lane) & 31);
    *(uint_t*)&As[e1] = pk;
  }
  __syncthreads();

  // ---- GEMM1: acc[32 rows][64 cols per wave], K = 384, no barriers ----
  const int b_off = (wave * 64 + m) * 32 + q * 8;  // frag base in W1s/W2s tile
  const int a_base = m * 32 + q * 8;

  floatx4 acc[2][4];
#pragma unroll
  for (int i = 0; i < 2; ++i)
#pragma unroll
    for (int j = 0; j < 4; ++j) acc[i][j] = (floatx4)0.0f;

  {
    bf16x8 bf0[4], bf1[4], af[2];
#pragma unroll
    for (int j = 0; j < 4; ++j)
      bf0[j] = *(const bf16x8*)(W1s + b_off + j * 512);
#pragma unroll
    for (int t = 0; t < 12; t += 2) {
#pragma unroll
      for (int j = 0; j < 4; ++j)
        bf1[j] = *(const bf16x8*)(W1s + (size_t)(t + 1) * 8192 + b_off + j * 512);
#pragma unroll
      for (int i = 0; i < 2; ++i)
        af[i] = *(const bf16x8*)&As[t * 1024 + a_base + i * 512];
#pragma unroll
      for (int i = 0; i < 2; ++i)
#pragma unroll
        for (int j = 0; j < 4; ++j)
          acc[i][j] = __builtin_amdgcn_mfma_f32_16x16x32_bf16(af[i], bf0[j],
                                                              acc[i][j], 0, 0, 0);
      if (t + 2 < 12) {
#pragma unroll
        for (int j = 0; j < 4; ++j)
          bf0[j] = *(const bf16x8*)(W1s + (size_t)(t + 2) * 8192 + b_off + j * 512);
      }
#pragma unroll
      for (int i = 0; i < 2; ++i)
        af[i] = *(const bf16x8*)&As[(t + 1) * 1024 + a_base + i * 512];
#pragma unroll
      for (int i = 0; i < 2; ++i)
#pragma unroll
        for (int j = 0; j < 4; ++j)
          acc[i][j] = __builtin_amdgcn_mfma_f32_16x16x32_bf16(af[i], bf1[j],
                                                              acc[i][j], 0, 0, 0);
    }
  }
  __syncthreads();  // all As reads done before HS overwrites the region

  // ---- epilogue1: bias + relu -> bf16 HS (aliases As; XOR-chunk swizzle) ----
  ushort_t* HS = As;  // 32 x 256 = 8192 elems = 16 KB
#pragma unroll
  for (int j = 0; j < 4; ++j) {
    int col = wave * 64 + j * 16 + m;
    float bv = b1[col];
    int cb = (col >> 3) & 3;
    int tb = (col >> 5) * 1024 + (col & 7);
#pragma unroll
    for (int i = 0; i < 2; ++i)
#pragma unroll
      for (int r = 0; r < 4; ++r) {
        int row = i * 16 + q * 4 + r;
        float v = acc[i][j][r] + bv;
        v = v > 0.0f ? v : 0.0f;
        int ch = cb ^ ((row >> 2) & 3);
        HS[tb + row * 32 + ch * 8] = f2bf(v);
      }
  }
  __syncthreads();

  // ---- GEMM2: K = 256, a-frags from HS, no barriers ----
  floatx4 acc2[2][4];
#pragma unroll
  for (int i = 0; i < 2; ++i)
#pragma unroll
    for (int j = 0; j < 4; ++j) acc2[i][j] = (floatx4)0.0f;

  {
    bf16x8 bf0[4], bf1[4], af[2];
#pragma unroll
    for (int j = 0; j < 4; ++j)
      bf0[j] = *(const bf16x8*)(W2s + b_off + j * 512);
#pragma unroll
    for (int t = 0; t < 8; t += 2) {
#pragma unroll
      for (int j = 0; j < 4; ++j)
        bf1[j] = *(const bf16x8*)(W2s + (size_t)(t + 1) * 8192 + b_off + j * 512);
#pragma unroll
      for (int i = 0; i < 2; ++i) {
        int row = m + 16 * i;
        int ch = q ^ ((row >> 2) & 3);
        af[i] = *(const bf16x8*)&HS[t * 1024 + row * 32 + ch * 8];
      }
#pragma unroll
      for (int i = 0; i < 2; ++i)
#pragma unroll
        for (int j = 0; j < 4; ++j)
          acc2[i][j] = __builtin_amdgcn_mfma_f32_16x16x32_bf16(af[i], bf0[j],
                                                               acc2[i][j], 0, 0, 0);
      if (t + 2 < 8) {
#pragma unroll
        for (int j = 0; j < 4; ++j)
          bf0[j] = *(const bf16x8*)(W2s + (size_t)(t + 2) * 8192 + b_off + j * 512);
      }
#pragma unroll
      for (int i = 0; i < 2; ++i) {
        int row = m + 16 * i;
        int ch = q ^ ((row >> 2) & 3);
        af[i] = *(const bf16x8*)&HS[(t + 1) * 1024 + row * 32 + ch * 8];
      }
#pragma unroll
      for (int i = 0; i < 2; ++i)
#pragma unroll
        for (int j = 0; j < 4; ++j)
          acc2[i][j] = __builtin_amdgcn_mfma_f32_16x16x32_bf16(af[i], bf1[j],
                                                               acc2[i][j], 0, 0, 0);
    }
  }

  // ---- epilogue2: bias + relu -> fp32 out ----
#pragma unroll
  for (int j = 0; j < 4; ++j) {
    int col = wave * 64 + j * 16 + m;
    float bv = b2[col];
#pragma unroll
    for (int i = 0; i < 2; ++i)
#pragma unroll
      for (int r = 0; r < 4; ++r) {
        int row = i * 16 + q * 4 + r;
        float v = acc2[i][j][r] + bv;
        v = v > 0.0f ? v : 0.0f;
        out[(size_t)(row0 + row) * DOUT_ + col] = v;
      }
  }
}

// ---------------- workspace layout ----------------

constexpr size_t OFF_W1S = 0;                  // 256*384*2 = 196608
constexpr size_t OFF_W2S = OFF_W1S + 196608;   // 256*256*2 = 131072
constexpr size_t WS_TOTAL = OFF_W2S + 131072;  // 320 KB

extern "C" void kernel_launch(void* const* d_in, const int* in_sizes, int n_in,
                              void* d_out, int out_size, void* d_ws, size_t ws_size,
                              hipStream_t stream) {
  const float* xyz1 = (const float*)d_in[0];
  const float* feat1 = (const float*)d_in[1];
  const float* xyz2 = (const float*)d_in[2];
  const float* feat2 = (const float*)d_in[3];
  const float* W1 = (const float*)d_in[4];
  const float* b1 = (const float*)d_in[5];
  const float* W2 = (const float*)d_in[6];
  const float* b2 = (const float*)d_in[7];

  if (ws_size < WS_TOTAL) return;

  char* ws = (char*)d_ws;
  ushort_t* W1s = (ushort_t*)(ws + OFF_W1S);
  ushort_t* W2s = (ushort_t*)(ws + OFF_W2S);

  prep_kernel<<<384, 256, 0, stream>>>(W1, W2, W1s, W2s);
  fused_kernel<<<M_ / 32, 256, 0, stream>>>(xyz1, xyz2, feat1, feat2, W1s, b1,
                                            W2s, b2, (float*)d_out);
}